// Round 1
// 749.570 us; speedup vs baseline: 1.2733x; 1.2733x over previous
//
#include <hip/hip_runtime.h>

// Problem constants (from reference)
#define Hh 256
#define Ww 256
#define Cc 32
#define NV 16
#define NN 4
#define NL 4

// One block = one (v, y) row, handling ALL NN novel views; threadIdx.x = x.
// Rationale (rocprof round 0): feats was fetched ~4-7x because the 4 blocks
// reading the same source rows (one per n) were 4096 dispatch slots apart and
// consecutive y rows round-robined across XCDs. Fusing n into the block plus an
// XCD-chunk swizzle makes the reuse window L2-resident. Nontemporal stores keep
// the 0.5-1.0 GB output stream from evicting feats out of L2/L3.
__global__ __launch_bounds__(256) void warp_kernel(
    const float* __restrict__ feats,      // [NV, C, H, W]
    const int*   __restrict__ depth,      // [NV, 1, H, W]
    const float* __restrict__ novel,      // [NN, 2]
    const float* __restrict__ vpos,       // [NV, 2]
    float*       __restrict__ out)        // [NN, NV, C, H, W]
{
    // Bijective XCD swizzle: 4096 blocks / 8 XCDs = 512 contiguous logical
    // blocks per XCD. XCD k processes logical ids [k*512, (k+1)*512).
    const int bid     = blockIdx.x;
    const int logical = (bid & 7) * (NV * Hh / 8) + (bid >> 3);
    const int v = logical >> 8;        // / Hh
    const int y = logical & (Hh - 1);
    const int x = threadIdx.x;

    const float vx = vpos[2 * v];
    const float vy = vpos[2 * v + 1];
    const float diop[NL] = {0.5f, 1.0f, 2.0f, 3.0f};

    const int* dv = depth + v * (Hh * Ww);

    // Winner source offset per novel view (highest l whose shifted source is
    // in-bounds and depth[src]==l), or -1. All 16 depth loads issued
    // independently (no short-circuit chain) so they pipeline.
    int winner[NN];
    #pragma unroll
    for (int n = 0; n < NN; ++n) {
        const float dvx = vx - novel[2 * n];
        const float dvy = vy - novel[2 * n + 1];
        int  off [NL];
        int  dval[NL];
        bool val [NL];
        #pragma unroll
        for (int l = 0; l < NL; ++l) {
            // match reference: round((vpos - novel) * diop * F_CAM*FEAT_DIM), RNE
            const int dx = (int)rintf(dvx * diop[l] * 128.0f);
            const int dy = (int)rintf(dvy * diop[l] * 128.0f);
            const int sy = y - dy;
            const int sx = x - dx;
            val[l] = (sy >= 0) & (sy < Hh) & (sx >= 0) & (sx < Ww);
            const int syc = min(max(sy, 0), Hh - 1);
            const int sxc = min(max(sx, 0), Ww - 1);
            off[l]  = syc * Ww + sxc;
            dval[l] = dv[off[l]];      // clamped => always safe
        }
        int w = -1;
        #pragma unroll
        for (int l = 0; l < NL; ++l)   // ascending: later layers overwrite
            if (val[l] && dval[l] == l) w = off[l];
        winner[n] = w;
    }

    const size_t plane  = (size_t)Hh * Ww;
    const size_t rowoff = (size_t)y * Ww + x;
    const float* fv = feats + (size_t)v * Cc * plane;

    float* ob[NN];
    #pragma unroll
    for (int n = 0; n < NN; ++n)
        ob[n] = out + ((size_t)(n * NV + v) * Cc) * plane + rowoff;

    #pragma unroll 4
    for (int c = 0; c < Cc; ++c) {
        const float* fc = fv + (size_t)c * plane;
        #pragma unroll
        for (int n = 0; n < NN; ++n) {
            float valf = 0.0f;
            const int wn = winner[n];
            if (wn >= 0) valf = fc[wn];
            // write-once stream: bypass/streaming hint, keep L2 for feats
            __builtin_nontemporal_store(valf, ob[n] + (size_t)c * plane);
        }
    }
}

extern "C" void kernel_launch(void* const* d_in, const int* in_sizes, int n_in,
                              void* d_out, int out_size, void* d_ws, size_t ws_size,
                              hipStream_t stream) {
    const float* feats = (const float*)d_in[0];
    const int*   depth = (const int*)d_in[1];
    const float* novel = (const float*)d_in[2];
    const float* vpos  = (const float*)d_in[3];
    float* out = (float*)d_out;

    dim3 grid(NV * Hh);   // 4096 blocks: (v, y), all n fused per block
    dim3 block(Ww);       // 256 threads: x
    warp_kernel<<<grid, block, 0, stream>>>(feats, depth, novel, vpos, out);
}